// Round 12
// baseline (6389.437 us; speedup 1.0000x reference)
//
#include <hip/hip_runtime.h>

// Problem constants
#define BB 256
#define SS 1024
#define II 64
#define HH 256
#define OO 24
#define NG 32     // groups (8 batch rows each)
#define NP 16     // parts per group (64 z-cols = 16 h-dims each)
#define BT 8

typedef __attribute__((ext_vector_type(8))) short short8;
typedef __attribute__((ext_vector_type(4))) float f32x4;
typedef unsigned long long ull;

#define H_CAP  8192
#define SP_CAP 16384

// LDS regions (per stream); padded to 96KB -> 1 block/CU
#define AHI_A 0
#define ALO_A 8192
#define AHI_B 16384
#define ALO_B 24576
#define ZL_A  32768
#define EL_A  36864
#define ZL_B  40960
#define EL_B  45056
#define SMEM_BYTES 98304

#define MFMA(a,b,c) __builtin_amdgcn_mfma_f32_16x16x32_bf16(a,b,c,0,0,0)

__device__ __forceinline__ float fsig(float x)  { return 1.f/(1.f+__expf(-x)); }
__device__ __forceinline__ float ftanh(float x) { return 1.f - 2.f/(__expf(2.f*x)+1.f); }

__device__ __forceinline__ unsigned rne_bf16(float x){
    unsigned u = __float_as_uint(x);
    return (u + 0x7FFFu + ((u>>16)&1u)) >> 16;
}
__device__ __forceinline__ void split_bf(float x, unsigned &hi, unsigned &lo){
    hi = rne_bf16(x);
    lo = rne_bf16(x - __uint_as_float(hi<<16));
}

union U4 { unsigned u[4]; short8 s; };

__device__ __forceinline__ void pack8(const float* v, short8 &H, short8 &L){
    U4 h_, l_;
    #pragma unroll
    for (int i = 0; i < 4; ++i) {
        unsigned a,b,c,d;
        split_bf(v[2*i], a, b); split_bf(v[2*i+1], c, d);
        h_.u[i] = a | (c<<16);
        l_.u[i] = b | (d<<16);
    }
    H = h_.s; L = l_.s;
}

// AGENT-scope relaxed atomics (only scheme proven deterministic+fast)
__device__ __forceinline__ ull cld(const ull* p){
    return __hip_atomic_load(p, __ATOMIC_RELAXED, __HIP_MEMORY_SCOPE_AGENT);
}
__device__ __forceinline__ void cst(ull* p, ull v){
    __hip_atomic_store(p, v, __ATOMIC_RELAXED, __HIP_MEMORY_SCOPE_AGENT);
}

// ---------------------------------------------------------------------------
// One stream-step: r10's proven structure at 8-batch group size.
// h words: hx[par][g][j=0..7][tau=tid]; word (j,tau) = h[tau>>5][(tau&31)*8+j]
// payload = (tag32 | hi16 | lo16). Consumer thread tid builds ONE frag word
// (batch tid>>5, dim-octet tid&31). MFMA A-tile rows 8..15 are garbage
// (they only affect unused C rows 8..15).
// ---------------------------------------------------------------------------
template<int AHI, int ALO, int ZLo, int ELo>
__device__ __forceinline__ void stream_step(
    int t, int tid, int w, int l, int p, int g, int b0,
    const float* __restrict__ x, char* smem, int* sdp,
    const short8* BwhH, const short8* BwhL,
    const short8* BwiH, const short8* BwiL,
    const short8* BwaH, const short8* BwaL,
    float bbv, float vj, float abj,
    ull* hx, ull* spx, ull* hv,
    float& c_state, float& h1v, float& h2v,
    float& m_run, float& l_run, float& ctx)
{
    // x frags from global (rows 8-15 duplicate rows 0-7; harmless)
    const int xb = l & 7, xoct = l >> 4;
    const float* xrow = x + ((size_t)(b0 + xb) * SS + t) * II + xoct*8;
    float xv0[8], xv1[8];
    *(float4*)&xv0[0] = *(const float4*)(xrow);
    *(float4*)&xv0[4] = *(const float4*)(xrow + 4);
    *(float4*)&xv1[0] = *(const float4*)(xrow + 32);
    *(float4*)&xv1[4] = *(const float4*)(xrow + 36);

    const int sb  = tid >> 4;      // valid for tid<128
    const int sjd = tid & 15;
    ull spr = 0;
    ull* spp = spx + (size_t)((t&1)*NG + g)*128 + (sb&7)*16 + sjd;
    if (t > 1 && tid < 128) spr = cld(spp);

    short8 XH0,XL0,XH1,XL1;
    pack8(xv0,XH0,XL0); pack8(xv1,XH1,XL1);
    f32x4 zacc = {bbv,bbv,bbv,bbv};
    zacc = MFMA(XH0,BwiH[0],zacc); zacc = MFMA(XH0,BwiL[0],zacc); zacc = MFMA(XL0,BwiH[0],zacc);
    zacc = MFMA(XH1,BwiH[1],zacc); zacc = MFMA(XH1,BwiL[1],zacc); zacc = MFMA(XL1,BwiH[1],zacc);

    if (t > 0) {
        const ull* hr = hx + ((size_t)(((t-1)&1)*NG + g)*8)*256 + tid;
        const unsigned texp = (unsigned)t;
        unsigned need = 0xFFu; int rounds = 0;
        while (true) {
            unsigned nn = 0;
            #pragma unroll
            for (int e = 0; e < 8; ++e)
                if (need & (1u<<e))
                    if ((unsigned)(hv[e]>>32) != texp) nn |= (1u<<e);
            need = nn;
            if (!need || *sdp) break;
            if (++rounds > H_CAP) { *sdp = 1; break; }
            #pragma unroll
            for (int e = 0; e < 8; ++e)
                if (need & (1u<<e)) hv[e] = cld(hr + e*256);
        }
        U4 H, L;
        #pragma unroll
        for (int i = 0; i < 4; ++i) {
            unsigned a = (unsigned)hv[2*i], b_ = (unsigned)hv[2*i+1];
            H.u[i] = (a>>16) | (b_ & 0xFFFF0000u);
            L.u[i] = (a & 0xFFFFu) | (b_<<16);
        }
        const int po_c = tid & 31, bb_c = tid >> 5;
        const int wa = ((po_c>>2)*64 + (po_c&3)*16 + bb_c)*16;
        *(short8*)(smem + AHI + wa) = H.s;
        *(short8*)(smem + ALO + wa) = L.s;
    }
    __syncthreads();                                   // barrier 1

    f32x4 zacc1 = {0.f,0.f,0.f,0.f}, eacc = {0.f,0.f,0.f,0.f};
    if (t > 0) {
        #pragma unroll
        for (int ks = 0; ks < 8; ++ks) {
            short8 ah = *(const short8*)(smem + AHI + ks*1024 + l*16);
            short8 al = *(const short8*)(smem + ALO + ks*1024 + l*16);
            if ((ks & 1) == 0) {
                zacc  = MFMA(ah,BwhH[ks],zacc);  zacc  = MFMA(ah,BwhL[ks],zacc);  zacc  = MFMA(al,BwhH[ks],zacc);
            } else {
                zacc1 = MFMA(ah,BwhH[ks],zacc1); zacc1 = MFMA(ah,BwhL[ks],zacc1); zacc1 = MFMA(al,BwhH[ks],zacc1);
            }
            if ((ks>>1) == w) {
                int jj = ks & 1;
                eacc = MFMA(ah,BwaH[jj],eacc); eacc = MFMA(ah,BwaL[jj],eacc); eacc = MFMA(al,BwaH[jj],eacc);
            }
        }
    }
    float* zl = (float*)(smem + ZLo);
    float* el = (float*)(smem + ELo);
    #pragma unroll
    for (int r = 0; r < 4; ++r) zl[w*256 + r*64 + l] = zacc[r] + zacc1[r];
    if (t > 0) {
        #pragma unroll
        for (int r = 0; r < 4; ++r) el[w*256 + r*64 + l] = eacc[r];
    }
    __syncthreads();                                   // barrier 2

    if (tid < 128) {
        const int zi = (sb&3)*64 + (sb>>2)*16 + sjd;   // (row sb, col sjd)
        float z0 = zl[0*256+zi], z1 = zl[1*256+zi], z2 = zl[2*256+zi], z3 = zl[3*256+zi];
        float ig = fsig(z0), fg = fsig(z1), gv = ftanh(z2), og = fsig(z3);
        c_state = fg*c_state + ig*gv;
        float h = og * ftanh(c_state);

        // publish h(t) tagged t+1 (critical path first)
        unsigned hhi, hlo; split_bf(h, hhi, hlo);
        const int D = p*16 + sjd;
        cst(hx + ((size_t)((t&1)*NG + g)*8 + (D&7))*256 + (sb*32 + (D>>3)),
            ((ull)(unsigned)(t+1) << 32) | (ull)((hhi<<16)|hlo));

        // score partial t-1
        if (t > 0) {
            float e = el[0*256+zi] + el[1*256+zi] + el[2*256+zi] + el[3*256+zi] + abj;
            float scp = vj * ftanh(e);
            scp += __shfl_xor(scp,1); scp += __shfl_xor(scp,2);
            scp += __shfl_xor(scp,4); scp += __shfl_xor(scp,8);
            if (sjd == 0)
                cst(spx + (size_t)(((t-1)&1)*NG + g)*128 + sb*16 + p,
                    ((ull)(unsigned)t << 32) | (ull)__float_as_uint(scp));
        }
        // softmax update t-2
        if (t > 1) {
            const unsigned texp2 = (unsigned)(t-1);
            int it = 0;
            while ((unsigned)(spr>>32) != texp2) {
                if (*sdp || ++it > SP_CAP) { *sdp = 1; break; }
                spr = cld(spp);
            }
            float s = __uint_as_float((unsigned)spr);
            s += __shfl_xor(s,1); s += __shfl_xor(s,2);
            s += __shfl_xor(s,4); s += __shfl_xor(s,8);
            float m_new = fmaxf(m_run, s);
            float sc = __expf(m_run - m_new);
            float wt = __expf(s - m_new);
            l_run = l_run*sc + wt;
            ctx   = ctx*sc + wt*h2v;
            m_run = m_new;
        }
        h2v = h1v; h1v = h;
    }
}

// epilogue A: h(SS-1) frags + energy MFMA; softmax SS-2; score SS-1
template<int AHI, int ALO, int ELo>
__device__ __forceinline__ void stream_epiA(
    int tid, int w, int l, int p, int g, char* smem, int* sdp,
    const short8* BwaH, const short8* BwaL,
    float vj, float abj, ull* hx, ull* spx, ull* hv,
    float& h1v, float& h2v, float& m_run, float& l_run, float& ctx)
{
    const ull* hr = hx + ((size_t)(((SS-1)&1)*NG + g)*8)*256 + tid;
    const unsigned texp = (unsigned)SS;
    unsigned need = 0xFFu; int rounds = 0;
    while (true) {
        unsigned nn = 0;
        #pragma unroll
        for (int e = 0; e < 8; ++e)
            if (need & (1u<<e))
                if ((unsigned)(hv[e]>>32) != texp) nn |= (1u<<e);
        need = nn;
        if (!need || *sdp) break;
        if (++rounds > H_CAP) { *sdp = 1; break; }
        #pragma unroll
        for (int e = 0; e < 8; ++e)
            if (need & (1u<<e)) hv[e] = cld(hr + e*256);
    }
    U4 H, L;
    #pragma unroll
    for (int i = 0; i < 4; ++i) {
        unsigned a = (unsigned)hv[2*i], b_ = (unsigned)hv[2*i+1];
        H.u[i] = (a>>16) | (b_ & 0xFFFF0000u);
        L.u[i] = (a & 0xFFFFu) | (b_<<16);
    }
    const int po_c = tid & 31, bb_c = tid >> 5;
    const int wa = ((po_c>>2)*64 + (po_c&3)*16 + bb_c)*16;
    *(short8*)(smem + AHI + wa) = H.s;
    *(short8*)(smem + ALO + wa) = L.s;
    __syncthreads();

    f32x4 eacc = {0.f,0.f,0.f,0.f};
    #pragma unroll
    for (int ks = 0; ks < 8; ++ks)
        if ((ks>>1) == w) {
            short8 ah = *(const short8*)(smem + AHI + ks*1024 + l*16);
            short8 al = *(const short8*)(smem + ALO + ks*1024 + l*16);
            int jj = ks & 1;
            eacc = MFMA(ah,BwaH[jj],eacc); eacc = MFMA(ah,BwaL[jj],eacc); eacc = MFMA(al,BwaH[jj],eacc);
        }
    float* el = (float*)(smem + ELo);
    #pragma unroll
    for (int r = 0; r < 4; ++r) el[w*256 + r*64 + l] = eacc[r];
    __syncthreads();

    if (tid < 128) {
        const int sb = tid >> 4, sjd = tid & 15;
        const int zi = (sb&3)*64 + (sb>>2)*16 + sjd;
        {   // softmax SS-2: slot SS&1, tag SS-1
            ull* spp = spx + (size_t)((SS&1)*NG + g)*128 + sb*16 + sjd;
            ull spr = cld(spp);
            const unsigned te2 = (unsigned)(SS-1);
            int it = 0;
            while ((unsigned)(spr>>32) != te2) {
                if (*sdp || ++it > SP_CAP) { *sdp = 1; break; }
                spr = cld(spp);
            }
            float s = __uint_as_float((unsigned)spr);
            s += __shfl_xor(s,1); s += __shfl_xor(s,2);
            s += __shfl_xor(s,4); s += __shfl_xor(s,8);
            float m_new = fmaxf(m_run, s);
            float sc = __expf(m_run - m_new);
            float wt = __expf(s - m_new);
            l_run = l_run*sc + wt;
            ctx   = ctx*sc + wt*h2v;
            m_run = m_new;
        }
        h2v = h1v;
        float e = el[0*256+zi] + el[1*256+zi] + el[2*256+zi] + el[3*256+zi] + abj;
        float scp = vj * ftanh(e);
        scp += __shfl_xor(scp,1); scp += __shfl_xor(scp,2);
        scp += __shfl_xor(scp,4); scp += __shfl_xor(scp,8);
        if (sjd == 0)
            cst(spx + (size_t)(((SS-1)&1)*NG + g)*128 + sb*16 + p,
                ((ull)(unsigned)SS << 32) | (ull)__float_as_uint(scp));
    }
}

__device__ __forceinline__ void stream_epiB(
    int tid, int p, int g, ull* spx, int* sdp,
    float h2v, float m_run, float l_run, float ctx, float* ctxg)
{
    if (tid < 128) {
        const int sb = tid >> 4, sjd = tid & 15;
        ull* spp = spx + (size_t)(((SS-1)&1)*NG + g)*128 + sb*16 + sjd;
        ull spr = cld(spp);
        const unsigned texp = (unsigned)SS;
        int it = 0;
        while ((unsigned)(spr>>32) != texp) {
            if (*sdp || ++it > SP_CAP) { *sdp = 1; break; }
            spr = cld(spp);
        }
        float s = __uint_as_float((unsigned)spr);
        s += __shfl_xor(s,1); s += __shfl_xor(s,2);
        s += __shfl_xor(s,4); s += __shfl_xor(s,8);
        float m_new = fmaxf(m_run, s);
        float sc = __expf(m_run - m_new);
        float wt = __expf(s - m_new);
        l_run = l_run*sc + wt;
        ctx   = ctx*sc + wt*h2v;
        ctxg[(size_t)(g*BT + sb)*HH + p*16 + sjd] = ctx / l_run;
    }
}

// ---------------------------------------------------------------------------
// Dual-stream kernel: block (p, gpair) runs groups 2*gpair, 2*gpair+1 in
// alternation; each stream's h-loads are issued during the other's compute.
// B-fragment registers (Wh/Wi/aW columns of part p) are SHARED by streams.
// ---------------------------------------------------------------------------
__global__ __launch_bounds__(256, 1)
void lstm_fused_kernel(const float* __restrict__ x,  const float* __restrict__ Wi,
                       const float* __restrict__ Wh, const float* __restrict__ bias,
                       const float* __restrict__ aW, const float* __restrict__ ab,
                       const float* __restrict__ av,
                       ull* __restrict__ hx, ull* __restrict__ spx,
                       float* __restrict__ ctxg)
{
    __shared__ __align__(16) char smem[SMEM_BYTES];
    __shared__ int sdead;

    const int tid = threadIdx.x;
    const int w = tid >> 6;
    const int l = tid & 63;
    const int p = blockIdx.x & 15;
    const int gA = (blockIdx.x >> 4) * 2;
    const int gB = gA + 1;
    const int b0A = gA * BT, b0B = gB * BT;

    if (tid == 0) sdead = 0;
    __syncthreads();

    const int n = l & 15;
    const int gcol = w*256 + p*16 + n;

    // ---- B-fragments (shared by both streams) ----------------------------
    short8 BwhH[8], BwhL[8];
    #pragma unroll
    for (int ks = 0; ks < 8; ++ks) {
        U4 H, L;
        #pragma unroll
        for (int i2 = 0; i2 < 4; ++i2) {
            int k0 = ks*32 + (l>>4)*8 + i2*2;
            unsigned h0,l0,h1,l1;
            split_bf(Wh[(size_t)k0*1024 + gcol], h0, l0);
            split_bf(Wh[(size_t)(k0+1)*1024 + gcol], h1, l1);
            H.u[i2] = h0 | (h1<<16);
            L.u[i2] = l0 | (l1<<16);
        }
        BwhH[ks] = H.s; BwhL[ks] = L.s;
    }
    short8 BwiH[2], BwiL[2];
    #pragma unroll
    for (int ks = 0; ks < 2; ++ks) {
        U4 H, L;
        #pragma unroll
        for (int i2 = 0; i2 < 4; ++i2) {
            int k0 = ks*32 + (l>>4)*8 + i2*2;
            unsigned h0,l0,h1,l1;
            split_bf(Wi[(size_t)k0*1024 + gcol], h0, l0);
            split_bf(Wi[(size_t)(k0+1)*1024 + gcol], h1, l1);
            H.u[i2] = h0 | (h1<<16);
            L.u[i2] = l0 | (l1<<16);
        }
        BwiH[ks] = H.s; BwiL[ks] = L.s;
    }
    short8 BwaH[2], BwaL[2];
    #pragma unroll
    for (int j = 0; j < 2; ++j) {
        int ks = 2*w + j;
        U4 H, L;
        #pragma unroll
        for (int i2 = 0; i2 < 4; ++i2) {
            int k0 = ks*32 + (l>>4)*8 + i2*2;
            unsigned h0,l0,h1,l1;
            split_bf(aW[(size_t)k0*256 + p*16 + n], h0, l0);
            split_bf(aW[(size_t)(k0+1)*256 + p*16 + n], h1, l1);
            H.u[i2] = h0 | (h1<<16);
            L.u[i2] = l0 | (l1<<16);
        }
        BwaH[j] = H.s; BwaL[j] = L.s;
    }
    const float bbv = bias[gcol];
    const float vj  = av[p*16 + (tid & 15)];
    const float abj = ab[p*16 + (tid & 15)];

    // per-stream state
    float cA=0.f, h1A=0.f, h2A=0.f, mA=-1.0e30f, lA=0.f, cxA=0.f;
    float cB=0.f, h1B=0.f, h2B=0.f, mB=-1.0e30f, lB=0.f, cxB=0.f;
    ull hvA[8], hvB[8];

    for (int t = 0; t < SS; ++t) {
        // issue B's h(t-1) loads; fly under A's compute
        if (t > 0) {
            const ull* hrB = hx + ((size_t)(((t-1)&1)*NG + gB)*8)*256 + tid;
            #pragma unroll
            for (int j = 0; j < 8; ++j) hvB[j] = cld(hrB + j*256);
        }
        stream_step<AHI_A,ALO_A,ZL_A,EL_A>(t, tid, w, l, p, gA, b0A, x, smem, &sdead,
            BwhH,BwhL,BwiH,BwiL,BwaH,BwaL, bbv,vj,abj, hx,spx, hvA,
            cA,h1A,h2A,mA,lA,cxA);

        // issue A's h(t) loads (tag t+1); fly under B's compute
        {
            const ull* hrA = hx + ((size_t)((t&1)*NG + gA)*8)*256 + tid;
            #pragma unroll
            for (int j = 0; j < 8; ++j) hvA[j] = cld(hrA + j*256);
        }
        stream_step<AHI_B,ALO_B,ZL_B,EL_B>(t, tid, w, l, p, gB, b0B, x, smem, &sdead,
            BwhH,BwhL,BwiH,BwiL,BwaH,BwaL, bbv,vj,abj, hx,spx, hvB,
            cB,h1B,h2B,mB,lB,cxB);
    }

    // epilogues: hvA already holds tag-SS loads (issued in last phase B)
    {
        const ull* hrB = hx + ((size_t)(((SS-1)&1)*NG + gB)*8)*256 + tid;
        #pragma unroll
        for (int j = 0; j < 8; ++j) hvB[j] = cld(hrB + j*256);
    }
    stream_epiA<AHI_A,ALO_A,EL_A>(tid,w,l,p,gA, smem,&sdead, BwaH,BwaL, vj,abj,
                                  hx,spx, hvA, h1A,h2A,mA,lA,cxA);
    stream_epiA<AHI_B,ALO_B,EL_B>(tid,w,l,p,gB, smem,&sdead, BwaH,BwaL, vj,abj,
                                  hx,spx, hvB, h1B,h2B,mB,lB,cxB);
    stream_epiB(tid,p,gA,spx,&sdead, h2A,mA,lA,cxA, ctxg);
    stream_epiB(tid,p,gB,spx,&sdead, h2B,mB,lB,cxB, ctxg);
}

// ---------------------------------------------------------------------------
__global__ __launch_bounds__(64)
void finalize_kernel(const float* __restrict__ ctxg, const float* __restrict__ fcW,
                     const float* __restrict__ fcb, float* __restrict__ out)
{
    __shared__ float cs[HH];
    const int b = blockIdx.x, tid = threadIdx.x;
    *(float4*)&cs[tid*4] = *(const float4*)&ctxg[(size_t)b*HH + tid*4];
    __syncthreads();
    if (tid < OO) {
        float a = fcb[tid];
        #pragma unroll 8
        for (int d = 0; d < HH; ++d) a = fmaf(cs[d], fcW[d*OO + tid], a);
        out[b*OO + tid] = a;
    }
}

// ---------------------------------------------------------------------------
extern "C" void kernel_launch(void* const* d_in, const int* in_sizes, int n_in,
                              void* d_out, int out_size, void* d_ws, size_t ws_size,
                              hipStream_t stream)
{
    const float* x      = (const float*)d_in[0];
    const float* Wi     = (const float*)d_in[1];
    const float* Wh     = (const float*)d_in[2];
    const float* bias   = (const float*)d_in[3];
    const float* attn_W = (const float*)d_in[4];
    const float* attn_b = (const float*)d_in[5];
    const float* v      = (const float*)d_in[6];
    const float* fc_W   = (const float*)d_in[7];
    const float* fc_b   = (const float*)d_in[8];
    float* out = (float*)d_out;

    // workspace: tagged h ring (1MB) + tagged sp ring (64KB) + ctx
    ull*   hx   = (ull*)d_ws;                  // 2*NG*8*256 = 131072 ull
    ull*   spx  = hx + 2*NG*8*256;             // 2*NG*128   = 8192 ull
    float* ctxg = (float*)(spx + 2*NG*128);    // 65536 floats

    // zero all tags each launch (graph-replay + poison safe)
    hipMemsetAsync(hx, 0, (2*NG*8*256 + 2*NG*128) * sizeof(ull), stream);

    lstm_fused_kernel<<<dim3(256), dim3(256), 0, stream>>>(
        x, Wi, Wh, bias, attn_W, attn_b, v, hx, spx, ctxg);
    finalize_kernel<<<dim3(BB), dim3(64), 0, stream>>>(ctxg, fc_W, fc_b, out);
}

// Round 15
// 3520.993 us; speedup vs baseline: 1.8147x; 1.8147x over previous
//
#include <hip/hip_runtime.h>

// Problem constants
#define BB 256
#define SS 1024
#define II 64
#define HH 256
#define OO 24
#define NG 16     // groups (16 batch rows each)
#define NP 16     // parts per group (64 z-cols = 16 h-dims each)
#define BT 16

typedef __attribute__((ext_vector_type(8))) short short8;
typedef __attribute__((ext_vector_type(4))) float f32x4;
typedef unsigned long long ull;

#define H_CAP  8192    // h tag-retry rounds (latches sdead)
#define SP_CAP 16384   // sp spin iterations (latches sdead)

// LDS byte offsets; total padded to 96KB to guarantee 1 block/CU
#define A_HI 0          // h hi frags  [8 kstep][64 lane][16B]
#define A_LO 8192
#define Z_OF 16384      // z  [gate q][reg r][lane]  f32   (4KB)
#define E_OF 20480      // energy partials, same layout    (4KB)
#define SMEM_BYTES 98304

#define MFMA(a,b,c) __builtin_amdgcn_mfma_f32_16x16x32_bf16(a,b,c,0,0,0)

__device__ __forceinline__ float fsig(float x)  { return 1.f/(1.f+__expf(-x)); }
__device__ __forceinline__ float ftanh(float x) { return 1.f - 2.f/(__expf(2.f*x)+1.f); }

__device__ __forceinline__ unsigned rne_bf16(float x){
    unsigned u = __float_as_uint(x);
    return (u + 0x7FFFu + ((u>>16)&1u)) >> 16;
}
__device__ __forceinline__ void split_bf(float x, unsigned &hi, unsigned &lo){
    hi = rne_bf16(x);
    lo = rne_bf16(x - __uint_as_float(hi<<16));
}

union U4 { unsigned u[4]; short8 s; };

__device__ __forceinline__ void pack8(const float* v, short8 &H, short8 &L){
    U4 h_, l_;
    #pragma unroll
    for (int i = 0; i < 4; ++i) {
        unsigned a,b,c,d;
        split_bf(v[2*i], a, b); split_bf(v[2*i+1], c, d);
        h_.u[i] = a | (c<<16);
        l_.u[i] = b | (d<<16);
    }
    H = h_.s; L = l_.s;
}

// AGENT-scope relaxed atomics (the only scheme proven deterministic: r3/r4/r6/r8/r10)
__device__ __forceinline__ ull cld(const ull* p){
    return __hip_atomic_load(p, __ATOMIC_RELAXED, __HIP_MEMORY_SCOPE_AGENT);
}
__device__ __forceinline__ void cst(ull* p, ull v){
    __hip_atomic_store(p, v, __ATOMIC_RELAXED, __HIP_MEMORY_SCOPE_AGENT);
}

// ---------------------------------------------------------------------------
// Fused xW + LSTM + attention scores + online-softmax context, MFMA bf16x3.
// grid = 256 (16 groups x 16 parts), block = 256 (4 waves).
// h exchange: tagged 8B words in CONSUMER-INTERLEAVED layout
//   hx[par][g][j][thread]  (j = 0..15)
// -> consumer load instruction j is fully coalesced (256 threads x 8B
//    contiguous); producer does one scattered fire-and-forget store.
// No flags, no producer drain, 2 barriers/step.
// ---------------------------------------------------------------------------
__global__ __launch_bounds__(256, 1)
void lstm_fused_kernel(const float* __restrict__ x,  const float* __restrict__ Wi,
                       const float* __restrict__ Wh, const float* __restrict__ bias,
                       const float* __restrict__ aW, const float* __restrict__ ab,
                       const float* __restrict__ av,
                       ull* __restrict__ hx, ull* __restrict__ spx,
                       float* __restrict__ ctxg)
{
    __shared__ __align__(16) char smem[SMEM_BYTES];
    __shared__ int sdead;

    const int tid = threadIdx.x;
    const int w = tid >> 6;          // wave = gate index
    const int l = tid & 63;
    const int p = blockIdx.x >> 4;   // part
    const int g = blockIdx.x & 15;   // group
    const int b0 = g * BT;

    if (tid == 0) sdead = 0;
    __syncthreads();

    const int n = l & 15;                    // frag col (B) / C col
    const int gcol = w*256 + p*16 + n;       // global z column for this lane
    const int gb = (l>>4)*4 + w;             // owned batch (gate phase)
    const int gd = n;                        // owned h-dim (local, 0..15)

    // ---- init: pre-split B operands into register fragments --------------
    short8 BwhH[8], BwhL[8];
    #pragma unroll
    for (int ks = 0; ks < 8; ++ks) {
        U4 H, L;
        #pragma unroll
        for (int i2 = 0; i2 < 4; ++i2) {
            int k0 = ks*32 + (l>>4)*8 + i2*2;
            unsigned h0,l0,h1,l1;
            split_bf(Wh[(size_t)k0*1024 + gcol], h0, l0);
            split_bf(Wh[(size_t)(k0+1)*1024 + gcol], h1, l1);
            H.u[i2] = h0 | (h1<<16);
            L.u[i2] = l0 | (l1<<16);
        }
        BwhH[ks] = H.s; BwhL[ks] = L.s;
    }
    short8 BwiH[2], BwiL[2];
    #pragma unroll
    for (int ks = 0; ks < 2; ++ks) {
        U4 H, L;
        #pragma unroll
        for (int i2 = 0; i2 < 4; ++i2) {
            int k0 = ks*32 + (l>>4)*8 + i2*2;
            unsigned h0,l0,h1,l1;
            split_bf(Wi[(size_t)k0*1024 + gcol], h0, l0);
            split_bf(Wi[(size_t)(k0+1)*1024 + gcol], h1, l1);
            H.u[i2] = h0 | (h1<<16);
            L.u[i2] = l0 | (l1<<16);
        }
        BwiH[ks] = H.s; BwiL[ks] = L.s;
    }
    short8 BwaH[2], BwaL[2];
    #pragma unroll
    for (int j = 0; j < 2; ++j) {
        int ks = 2*w + j;     // this wave's energy k-steps
        U4 H, L;
        #pragma unroll
        for (int i2 = 0; i2 < 4; ++i2) {
            int k0 = ks*32 + (l>>4)*8 + i2*2;
            unsigned h0,l0,h1,l1;
            split_bf(aW[(size_t)k0*256 + p*16 + n], h0, l0);
            split_bf(aW[(size_t)(k0+1)*256 + p*16 + n], h1, l1);
            H.u[i2] = h0 | (h1<<16);
            L.u[i2] = l0 | (l1<<16);
        }
        BwaH[j] = H.s; BwaL[j] = L.s;
    }
    const float bb  = bias[gcol];
    const float vj  = av[p*16 + gd];
    const float abj = ab[p*16 + gd];

    // consumer mapping: thread tid reads words j=0..15 at hx[..][j][tid];
    // word j = (batch pbase+(j>>3), dim po*8+(j&7))
    const int po    = tid >> 3;        // dim octet 0..31
    const int pbase = (tid & 7) * 2;   // even batch
    const int wa0 = (po>>2)*1024 + ((po&3)*16 + pbase)*16;
    const int wa1 = wa0 + 16;

    // producer mapping: (batch gb, global dim D) -> slot (j_pub, tau)
    const int D = p*16 + gd;
    const int tau   = (gb>>1) | ((D>>3)<<3);
    const int j_pub = ((gb&1)<<3) | (D&7);

    const int xb = l & 15;
    const int xoct = l >> 4;           // 0..3: frag k-octet within kstep

    float c_state = 0.f, h1v = 0.f, h2v = 0.f;
    float m_run = -1.0e30f, l_run = 0.f, ctx = 0.f;

    float* zl = (float*)(smem + Z_OF);
    float* el = (float*)(smem + E_OF);

    for (int t = 0; t < SS; ++t) {
        const int par = t & 1;
        // ---- x loads first -----------------------------------------------
        const float* xrow = x + ((size_t)(b0 + xb) * SS + t) * II + xoct*8;
        float xv0[8], xv1[8];
        *(float4*)&xv0[0] = *(const float4*)(xrow);
        *(float4*)&xv0[4] = *(const float4*)(xrow + 4);
        *(float4*)&xv1[0] = *(const float4*)(xrow + 32);
        *(float4*)&xv1[4] = *(const float4*)(xrow + 36);

        // ---- issue coalesced tagged h(t-1) loads (j-interleaved) ---------
        ull hv[16]; ull spr = 0;
        const ull* hr = hx + ((size_t)(((t-1)&1)*NG + g) * 16) * 256 + tid;
        if (t > 0) {
            #pragma unroll
            for (int j = 0; j < 16; ++j) hv[j] = cld(hr + j*256);
        }
        ull* spp = spx + (size_t)par*4096 + g*256 + gb*16 + gd;
        if (t > 1) spr = cld(spp);

        // ---- x pack + x MFMA (overlaps h-load flight & store visibility) -
        short8 XH0, XL0, XH1, XL1;
        pack8(xv0, XH0, XL0);
        pack8(xv1, XH1, XL1);
        f32x4 zacc = {bb,bb,bb,bb};
        zacc = MFMA(XH0, BwiH[0], zacc);
        zacc = MFMA(XH0, BwiL[0], zacc);
        zacc = MFMA(XL0, BwiH[0], zacc);
        zacc = MFMA(XH1, BwiH[1], zacc);
        zacc = MFMA(XH1, BwiL[1], zacc);
        zacc = MFMA(XL1, BwiH[1], zacc);

        // ---- tag check + coalesced retry rounds --------------------------
        if (t > 0) {
            const unsigned texp = (unsigned)t;   // h(t-1) tagged t
            unsigned need = 0xFFFFu;
            int rounds = 0;
            while (true) {
                unsigned nn = 0;
                #pragma unroll
                for (int e = 0; e < 16; ++e)
                    if (need & (1u<<e))
                        if ((unsigned)(hv[e]>>32) != texp) nn |= (1u<<e);
                need = nn;
                if (!need || sdead) break;
                if (++rounds > H_CAP) { sdead = 1; break; }
                #pragma unroll
                for (int e = 0; e < 16; ++e)
                    if (need & (1u<<e)) hv[e] = cld(hr + e*256);
            }
            float va[16];
            #pragma unroll
            for (int e = 0; e < 16; ++e) va[e] = __uint_as_float((unsigned)hv[e]);
            short8 H0,L0,H1,L1;
            pack8(&va[0], H0, L0);
            pack8(&va[8], H1, L1);
            *(short8*)(smem + A_HI + wa0) = H0;
            *(short8*)(smem + A_LO + wa0) = L0;
            *(short8*)(smem + A_HI + wa1) = H1;
            *(short8*)(smem + A_LO + wa1) = L1;
        }
        __syncthreads();                                   // barrier A

        // ---- MFMA: z += h@Wh, energy partial -----------------------------
        f32x4 zacc1 = {0.f,0.f,0.f,0.f};
        f32x4 eacc  = {0.f,0.f,0.f,0.f};
        if (t > 0) {
            #pragma unroll
            for (int ks = 0; ks < 8; ++ks) {
                short8 ah = *(const short8*)(smem + A_HI + ks*1024 + l*16);
                short8 al = *(const short8*)(smem + A_LO + ks*1024 + l*16);
                if ((ks & 1) == 0) {
                    zacc = MFMA(ah, BwhH[ks], zacc);
                    zacc = MFMA(ah, BwhL[ks], zacc);
                    zacc = MFMA(al, BwhH[ks], zacc);
                } else {
                    zacc1 = MFMA(ah, BwhH[ks], zacc1);
                    zacc1 = MFMA(ah, BwhL[ks], zacc1);
                    zacc1 = MFMA(al, BwhH[ks], zacc1);
                }
                if ((ks>>1) == w) {
                    int jj = ks & 1;
                    eacc = MFMA(ah, BwaH[jj], eacc);
                    eacc = MFMA(ah, BwaL[jj], eacc);
                    eacc = MFMA(al, BwaH[jj], eacc);
                }
            }
        }
        #pragma unroll
        for (int r = 0; r < 4; ++r) zl[w*256 + r*64 + l] = zacc[r] + zacc1[r];
        if (t > 0) {
            #pragma unroll
            for (int r = 0; r < 4; ++r) el[w*256 + r*64 + l] = eacc[r];
        }
        __syncthreads();                                   // barrier B

        // ---- gates -------------------------------------------------------
        float z0 = zl[0*256 + w*64 + l];
        float z1 = zl[1*256 + w*64 + l];
        float z2 = zl[2*256 + w*64 + l];
        float z3 = zl[3*256 + w*64 + l];
        float ig = fsig(z0), fg = fsig(z1), gv = ftanh(z2), og = fsig(z3);
        c_state = fg*c_state + ig*gv;
        float h = og * ftanh(c_state);

        // ---- publish h(t) tagged t+1, fire-and-forget (critical path) ----
        cst(hx + ((size_t)(par*NG + g) * 16 + j_pub) * 256 + tau,
            ((ull)(unsigned)(t+1) << 32) | (ull)__float_as_uint(h));

        // ---- off critical path: score partial t-1, softmax update t-2 ----
        if (t > 0) {
            float e = el[0*256+w*64+l] + el[1*256+w*64+l]
                    + el[2*256+w*64+l] + el[3*256+w*64+l] + abj;
            float scp = vj * ftanh(e);
            scp += __shfl_xor(scp,1); scp += __shfl_xor(scp,2);
            scp += __shfl_xor(scp,4); scp += __shfl_xor(scp,8);
            if (gd == 0)
                cst(spx + (size_t)((t-1)&1)*4096 + g*256 + gb*16 + p,
                    ((ull)(unsigned)t << 32) | (ull)__float_as_uint(scp));
        }
        if (t > 1) {
            const unsigned texp = (unsigned)(t-1);
            int it = 0;
            while ((unsigned)(spr>>32) != texp) {
                if (sdead || ++it > SP_CAP) { sdead = 1; break; }
                spr = cld(spp);
            }
            float s = __uint_as_float((unsigned)spr);
            s += __shfl_xor(s,1); s += __shfl_xor(s,2);
            s += __shfl_xor(s,4); s += __shfl_xor(s,8);
            float m_new = fmaxf(m_run, s);
            float sc = __expf(m_run - m_new);
            float wt = __expf(s - m_new);
            l_run = l_run*sc + wt;
            ctx   = ctx*sc + wt*h2v;
            m_run = m_new;
        }
        h2v = h1v; h1v = h;
    }

    // ---- epilogue A: energy/score for SS-1, softmax update for SS-2 ------
    {
        const ull* hr = hx + ((size_t)(((SS-1)&1)*NG + g) * 16) * 256 + tid;
        ull hv[16];
        #pragma unroll
        for (int j = 0; j < 16; ++j) hv[j] = cld(hr + j*256);
        const unsigned texp = (unsigned)SS;
        unsigned need = 0xFFFFu;
        int rounds = 0;
        while (true) {
            unsigned nn = 0;
            #pragma unroll
            for (int e = 0; e < 16; ++e)
                if (need & (1u<<e))
                    if ((unsigned)(hv[e]>>32) != texp) nn |= (1u<<e);
            need = nn;
            if (!need || sdead) break;
            if (++rounds > H_CAP) { sdead = 1; break; }
            #pragma unroll
            for (int e = 0; e < 16; ++e)
                if (need & (1u<<e)) hv[e] = cld(hr + e*256);
        }
        float va[16];
        #pragma unroll
        for (int e = 0; e < 16; ++e) va[e] = __uint_as_float((unsigned)hv[e]);
        short8 H0,L0,H1,L1;
        pack8(&va[0], H0, L0);
        pack8(&va[8], H1, L1);
        *(short8*)(smem + A_HI + wa0) = H0;
        *(short8*)(smem + A_LO + wa0) = L0;
        *(short8*)(smem + A_HI + wa1) = H1;
        *(short8*)(smem + A_LO + wa1) = L1;
        __syncthreads();

        f32x4 eacc = {0.f,0.f,0.f,0.f};
        #pragma unroll
        for (int ks = 0; ks < 8; ++ks) {
            if ((ks>>1) == w) {
                short8 ah = *(const short8*)(smem + A_HI + ks*1024 + l*16);
                short8 al = *(const short8*)(smem + A_LO + ks*1024 + l*16);
                int jj = ks & 1;
                eacc = MFMA(ah, BwaH[jj], eacc);
                eacc = MFMA(ah, BwaL[jj], eacc);
                eacc = MFMA(al, BwaH[jj], eacc);
            }
        }
        #pragma unroll
        for (int r = 0; r < 4; ++r) el[w*256 + r*64 + l] = eacc[r];
        __syncthreads();

        {   // softmax update for SS-2 (sp slot SS&1, tag SS-1)
            ull* spp2 = spx + (size_t)(SS&1)*4096 + g*256 + gb*16 + gd;
            ull spr = cld(spp2);
            const unsigned te2 = (unsigned)(SS-1);
            int it = 0;
            while ((unsigned)(spr>>32) != te2) {
                if (sdead || ++it > SP_CAP) { sdead = 1; break; }
                spr = cld(spp2);
            }
            float s = __uint_as_float((unsigned)spr);
            s += __shfl_xor(s,1); s += __shfl_xor(s,2);
            s += __shfl_xor(s,4); s += __shfl_xor(s,8);
            float m_new = fmaxf(m_run, s);
            float sc = __expf(m_run - m_new);
            float wt = __expf(s - m_new);
            l_run = l_run*sc + wt;
            ctx   = ctx*sc + wt*h2v;
            m_run = m_new;
        }
        h2v = h1v;
        // score for SS-1 (tag SS)
        float e = el[0*256+w*64+l] + el[1*256+w*64+l]
                + el[2*256+w*64+l] + el[3*256+w*64+l] + abj;
        float scp = vj * ftanh(e);
        scp += __shfl_xor(scp,1); scp += __shfl_xor(scp,2);
        scp += __shfl_xor(scp,4); scp += __shfl_xor(scp,8);
        if (gd == 0)
            cst(spx + (size_t)((SS-1)&1)*4096 + g*256 + gb*16 + p,
                ((ull)(unsigned)SS << 32) | (ull)__float_as_uint(scp));
    }

    // ---- epilogue B: softmax update for SS-1, write context --------------
    {
        ull* spp2 = spx + (size_t)((SS-1)&1)*4096 + g*256 + gb*16 + gd;
        ull spr = cld(spp2);
        const unsigned texp = (unsigned)SS;
        int it = 0;
        while ((unsigned)(spr>>32) != texp) {
            if (sdead || ++it > SP_CAP) { sdead = 1; break; }
            spr = cld(spp2);
        }
        float s = __uint_as_float((unsigned)spr);
        s += __shfl_xor(s,1); s += __shfl_xor(s,2);
        s += __shfl_xor(s,4); s += __shfl_xor(s,8);
        float m_new = fmaxf(m_run, s);
        float sc = __expf(m_run - m_new);
        float wt = __expf(s - m_new);
        l_run = l_run*sc + wt;
        ctx   = ctx*sc + wt*h2v;   // h2v == h(SS-1)

        ctxg[(size_t)(b0+gb)*HH + p*16 + gd] = ctx / l_run;
    }
}

// ---------------------------------------------------------------------------
__global__ __launch_bounds__(64)
void finalize_kernel(const float* __restrict__ ctxg, const float* __restrict__ fcW,
                     const float* __restrict__ fcb, float* __restrict__ out)
{
    __shared__ float cs[HH];
    const int b = blockIdx.x, tid = threadIdx.x;
    *(float4*)&cs[tid*4] = *(const float4*)&ctxg[(size_t)b*HH + tid*4];
    __syncthreads();
    if (tid < OO) {
        float a = fcb[tid];
        #pragma unroll 8
        for (int d = 0; d < HH; ++d) a = fmaf(cs[d], fcW[d*OO + tid], a);
        out[b*OO + tid] = a;
    }
}

// ---------------------------------------------------------------------------
extern "C" void kernel_launch(void* const* d_in, const int* in_sizes, int n_in,
                              void* d_out, int out_size, void* d_ws, size_t ws_size,
                              hipStream_t stream)
{
    const float* x      = (const float*)d_in[0];
    const float* Wi     = (const float*)d_in[1];
    const float* Wh     = (const float*)d_in[2];
    const float* bias   = (const float*)d_in[3];
    const float* attn_W = (const float*)d_in[4];
    const float* attn_b = (const float*)d_in[5];
    const float* v      = (const float*)d_in[6];
    const float* fc_W   = (const float*)d_in[7];
    const float* fc_b   = (const float*)d_in[8];
    float* out = (float*)d_out;

    // workspace: tagged h ring (1MB, consumer-interleaved) + tagged sp ring + ctx
    ull*   hx   = (ull*)d_ws;                  // 2*NG*16*256 = 131072 ull
    ull*   spx  = hx + 2*NG*16*256;            // 2*NG*256    = 8192 ull
    float* ctxg = (float*)(spx + 8192);        // 65536 floats

    // zero all tags each launch (graph-replay + poison safe)
    hipMemsetAsync(hx, 0, (2*NG*16*256 + 8192) * sizeof(ull), stream);

    lstm_fused_kernel<<<dim3(NG*NP), dim3(256), 0, stream>>>(
        x, Wi, Wh, bias, attn_W, attn_b, v, hx, spx, ctxg);
    finalize_kernel<<<dim3(BB), dim3(64), 0, stream>>>(ctxg, fc_W, fc_b, out);
}

// Round 16
// 3473.103 us; speedup vs baseline: 1.8397x; 1.0138x over previous
//
#include <hip/hip_runtime.h>

// Problem constants
#define BB 256
#define SS 1024
#define II 64
#define HH 256
#define OO 24
#define NG 32     // groups (8 batch rows each)
#define NP 8      // parts per group (128 z-cols = 32 h-dims each)
#define BT 8

typedef __attribute__((ext_vector_type(8))) short short8;
typedef __attribute__((ext_vector_type(4))) float f32x4;
typedef unsigned long long ull;

#define H_CAP  8192    // h tag-retry rounds (latches sdead)
#define SP_CAP 16384   // sp spin iterations (latches sdead)

// LDS byte offsets; total padded to 96KB to guarantee 1 block/CU
#define A_HI 0          // h hi frags  [8 kstep][64 lane][16B]  (8KB)
#define A_LO 8192
#define Z_OF 16384      // z  [gate w][tile][reg][lane] f32     (8KB)
#define E_OF 24576      // energy partials, same layout         (8KB)
#define SMEM_BYTES 98304

#define MFMA(a,b,c) __builtin_amdgcn_mfma_f32_16x16x32_bf16(a,b,c,0,0,0)

__device__ __forceinline__ float fsig(float x)  { return 1.f/(1.f+__expf(-x)); }
__device__ __forceinline__ float ftanh(float x) { return 1.f - 2.f/(__expf(2.f*x)+1.f); }

__device__ __forceinline__ unsigned rne_bf16(float x){
    unsigned u = __float_as_uint(x);
    return (u + 0x7FFFu + ((u>>16)&1u)) >> 16;
}
__device__ __forceinline__ void split_bf(float x, unsigned &hi, unsigned &lo){
    hi = rne_bf16(x);
    lo = rne_bf16(x - __uint_as_float(hi<<16));
}

union U4 { unsigned u[4]; short8 s; };

__device__ __forceinline__ void pack8(const float* v, short8 &H, short8 &L){
    U4 h_, l_;
    #pragma unroll
    for (int i = 0; i < 4; ++i) {
        unsigned a,b,c,d;
        split_bf(v[2*i], a, b); split_bf(v[2*i+1], c, d);
        h_.u[i] = a | (c<<16);
        l_.u[i] = b | (d<<16);
    }
    H = h_.s; L = l_.s;
}

// AGENT-scope relaxed atomics (the only scheme proven deterministic)
__device__ __forceinline__ ull cld(const ull* p){
    return __hip_atomic_load(p, __ATOMIC_RELAXED, __HIP_MEMORY_SCOPE_AGENT);
}
__device__ __forceinline__ void cst(ull* p, ull v){
    __hip_atomic_store(p, v, __ATOMIC_RELAXED, __HIP_MEMORY_SCOPE_AGENT);
}

// ---------------------------------------------------------------------------
// Fused xW + LSTM + attention scores + online-softmax context, MFMA bf16x3.
// grid = 256 (32 groups x 8 parts), block = 256 (4 waves).
// Part owns 32 h-dims (128 z-cols, 2 column-tiles/wave); B-frags ~190 VGPR
// (1 wave/SIMD -> 512 budget). h exchange: r10 protocol, tagged 8B words
// (tag32 | hi16 | lo16) in consumer-interleaved layout hx[par][g][j=0..7][tid].
// Each consumer thread's 8 words come from ONE producer part -> convoy = 8.
// ---------------------------------------------------------------------------
__global__ __launch_bounds__(256, 1)
void lstm_fused_kernel(const float* __restrict__ x,  const float* __restrict__ Wi,
                       const float* __restrict__ Wh, const float* __restrict__ bias,
                       const float* __restrict__ aW, const float* __restrict__ ab,
                       const float* __restrict__ av,
                       ull* __restrict__ hx, ull* __restrict__ spx,
                       float* __restrict__ ctxg)
{
    __shared__ __align__(16) char smem[SMEM_BYTES];
    __shared__ int sdead;

    const int tid = threadIdx.x;
    const int w = tid >> 6;          // wave = gate index
    const int l = tid & 63;
    const int p = blockIdx.x & 7;    // part  0..7
    const int g = blockIdx.x >> 3;   // group 0..31
    const int b0 = g * BT;

    if (tid == 0) sdead = 0;
    __syncthreads();

    const int n = l & 15;            // frag col within tile

    // gate/score-phase ownership: (batch sb, local dim sjd 0..31)
    const int sb  = tid >> 5;
    const int sjd = tid & 31;

    // ---- init: pre-split B operands (2 column-tiles per wave) ------------
    short8 BwhH[16], BwhL[16];       // [tile][kstep]
    #pragma unroll
    for (int ti = 0; ti < 2; ++ti) {
        const int gc = w*256 + p*32 + ti*16 + n;
        #pragma unroll
        for (int ks = 0; ks < 8; ++ks) {
            U4 H, L;
            #pragma unroll
            for (int i2 = 0; i2 < 4; ++i2) {
                int k0 = ks*32 + (l>>4)*8 + i2*2;
                unsigned h0,l0,h1,l1;
                split_bf(Wh[(size_t)k0*1024 + gc], h0, l0);
                split_bf(Wh[(size_t)(k0+1)*1024 + gc], h1, l1);
                H.u[i2] = h0 | (h1<<16);
                L.u[i2] = l0 | (l1<<16);
            }
            BwhH[ti*8+ks] = H.s; BwhL[ti*8+ks] = L.s;
        }
    }
    short8 BwiH[4], BwiL[4];         // [tile][kstep(2)]
    #pragma unroll
    for (int ti = 0; ti < 2; ++ti) {
        const int gc = w*256 + p*32 + ti*16 + n;
        #pragma unroll
        for (int ks = 0; ks < 2; ++ks) {
            U4 H, L;
            #pragma unroll
            for (int i2 = 0; i2 < 4; ++i2) {
                int k0 = ks*32 + (l>>4)*8 + i2*2;
                unsigned h0,l0,h1,l1;
                split_bf(Wi[(size_t)k0*1024 + gc], h0, l0);
                split_bf(Wi[(size_t)(k0+1)*1024 + gc], h1, l1);
                H.u[i2] = h0 | (h1<<16);
                L.u[i2] = l0 | (l1<<16);
            }
            BwiH[ti*2+ks] = H.s; BwiL[ti*2+ks] = L.s;
        }
    }
    short8 BwaH[4], BwaL[4];         // [tile][j(2)], kstep = 2w+j
    #pragma unroll
    for (int ti = 0; ti < 2; ++ti) {
        #pragma unroll
        for (int j = 0; j < 2; ++j) {
            int ks = 2*w + j;
            U4 H, L;
            #pragma unroll
            for (int i2 = 0; i2 < 4; ++i2) {
                int k0 = ks*32 + (l>>4)*8 + i2*2;
                unsigned h0,l0,h1,l1;
                split_bf(aW[(size_t)k0*256 + p*32 + ti*16 + n], h0, l0);
                split_bf(aW[(size_t)(k0+1)*256 + p*32 + ti*16 + n], h1, l1);
                H.u[i2] = h0 | (h1<<16);
                L.u[i2] = l0 | (l1<<16);
            }
            BwaH[ti*2+j] = H.s; BwaL[ti*2+j] = L.s;
        }
    }
    const float bb0 = bias[w*256 + p*32 + n];
    const float bb1 = bias[w*256 + p*32 + 16 + n];
    const float vj  = av[p*32 + sjd];
    const float abj = ab[p*32 + sjd];

    // consumer mapping: thread tid loads words j=0..7 at hx[..][j][tid];
    // word (j,tid) = h[batch tid>>5][dim (tid&31)*8 + j]
    const int po_c = tid & 31, bb_c = tid >> 5;
    const int wa = ((po_c>>2)*64 + (po_c&3)*16 + bb_c)*16;

    // producer mapping: (sb, D = p*32+sjd) -> (j_pub = D&7, tau = sb*32+(D>>3))
    const int D = p*32 + sjd;
    const int j_pub = D & 7;
    const int tau   = sb*32 + (D>>3);

    const int xb = l & 7;            // rows 8-15 duplicate rows 0-7 (unused C)
    const int xoct = l >> 4;

    float c_state = 0.f, h1v = 0.f, h2v = 0.f;
    float m_run = -1.0e30f, l_run = 0.f, ctx = 0.f;

    float* zl = (float*)(smem + Z_OF);
    float* el = (float*)(smem + E_OF);
    const int zi = (sjd>>4)*256 + (sb&3)*64 + (sb>>2)*16 + (sjd&15);

    for (int t = 0; t < SS; ++t) {
        const int par = t & 1;
        // ---- x loads -----------------------------------------------------
        const float* xrow = x + ((size_t)(b0 + xb) * SS + t) * II + xoct*8;
        float xv0[8], xv1[8];
        *(float4*)&xv0[0] = *(const float4*)(xrow);
        *(float4*)&xv0[4] = *(const float4*)(xrow + 4);
        *(float4*)&xv1[0] = *(const float4*)(xrow + 32);
        *(float4*)&xv1[4] = *(const float4*)(xrow + 36);

        // ---- issue coalesced tagged h(t-1) loads -------------------------
        ull hv[8]; ull spr = 0;
        const ull* hr = hx + ((size_t)(((t-1)&1)*NG + g) * 8) * 256 + tid;
        if (t > 0) {
            #pragma unroll
            for (int j = 0; j < 8; ++j) hv[j] = cld(hr + j*256);
        }
        ull* spp = spx + (size_t)par*2048 + g*64 + sb*8 + (sjd&7);
        if (t > 1) spr = cld(spp);

        // ---- x pack + x MFMA (overlaps h-load flight) --------------------
        short8 XH0, XL0, XH1, XL1;
        pack8(xv0, XH0, XL0);
        pack8(xv1, XH1, XL1);
        f32x4 zA0 = {bb0,bb0,bb0,bb0}, zA1 = {0.f,0.f,0.f,0.f};
        f32x4 zB0 = {bb1,bb1,bb1,bb1}, zB1 = {0.f,0.f,0.f,0.f};
        zA0 = MFMA(XH0, BwiH[0], zA0); zA0 = MFMA(XH0, BwiL[0], zA0); zA0 = MFMA(XL0, BwiH[0], zA0);
        zA0 = MFMA(XH1, BwiH[1], zA0); zA0 = MFMA(XH1, BwiL[1], zA0); zA0 = MFMA(XL1, BwiH[1], zA0);
        zB0 = MFMA(XH0, BwiH[2], zB0); zB0 = MFMA(XH0, BwiL[2], zB0); zB0 = MFMA(XL0, BwiH[2], zB0);
        zB0 = MFMA(XH1, BwiH[3], zB0); zB0 = MFMA(XH1, BwiL[3], zB0); zB0 = MFMA(XL1, BwiH[3], zB0);

        // ---- tag check + coalesced retry rounds --------------------------
        if (t > 0) {
            const unsigned texp = (unsigned)t;   // h(t-1) tagged t
            unsigned need = 0xFFu;
            int rounds = 0;
            while (true) {
                unsigned nn = 0;
                #pragma unroll
                for (int e = 0; e < 8; ++e)
                    if (need & (1u<<e))
                        if ((unsigned)(hv[e]>>32) != texp) nn |= (1u<<e);
                need = nn;
                if (!need || sdead) break;
                if (++rounds > H_CAP) { sdead = 1; break; }
                #pragma unroll
                for (int e = 0; e < 8; ++e)
                    if (need & (1u<<e)) hv[e] = cld(hr + e*256);
            }
            // frag build from (hi|lo) payloads — bit ops only
            U4 H, L;
            #pragma unroll
            for (int i = 0; i < 4; ++i) {
                unsigned a = (unsigned)hv[2*i], b_ = (unsigned)hv[2*i+1];
                H.u[i] = (a>>16) | (b_ & 0xFFFF0000u);
                L.u[i] = (a & 0xFFFFu) | (b_<<16);
            }
            *(short8*)(smem + A_HI + wa) = H.s;
            *(short8*)(smem + A_LO + wa) = L.s;
        }
        __syncthreads();                                   // barrier A

        // ---- MFMA: z += h@Wh (2 tiles), energy partial -------------------
        f32x4 eA = {0.f,0.f,0.f,0.f}, eB = {0.f,0.f,0.f,0.f};
        if (t > 0) {
            #pragma unroll
            for (int ks = 0; ks < 8; ++ks) {
                short8 ah = *(const short8*)(smem + A_HI + ks*1024 + l*16);
                short8 al = *(const short8*)(smem + A_LO + ks*1024 + l*16);
                if ((ks & 1) == 0) {
                    zA0 = MFMA(ah, BwhH[ks], zA0);   zA0 = MFMA(ah, BwhL[ks], zA0);   zA0 = MFMA(al, BwhH[ks], zA0);
                    zB0 = MFMA(ah, BwhH[8+ks], zB0); zB0 = MFMA(ah, BwhL[8+ks], zB0); zB0 = MFMA(al, BwhH[8+ks], zB0);
                } else {
                    zA1 = MFMA(ah, BwhH[ks], zA1);   zA1 = MFMA(ah, BwhL[ks], zA1);   zA1 = MFMA(al, BwhH[ks], zA1);
                    zB1 = MFMA(ah, BwhH[8+ks], zB1); zB1 = MFMA(ah, BwhL[8+ks], zB1); zB1 = MFMA(al, BwhH[8+ks], zB1);
                }
                if ((ks>>1) == w) {
                    int jj = ks & 1;
                    eA = MFMA(ah, BwaH[jj], eA);   eA = MFMA(ah, BwaL[jj], eA);   eA = MFMA(al, BwaH[jj], eA);
                    eB = MFMA(ah, BwaH[2+jj], eB); eB = MFMA(ah, BwaL[2+jj], eB); eB = MFMA(al, BwaH[2+jj], eB);
                }
            }
        }
        #pragma unroll
        for (int r = 0; r < 4; ++r) {
            zl[w*512 +       r*64 + l] = zA0[r] + zA1[r];
            zl[w*512 + 256 + r*64 + l] = zB0[r] + zB1[r];
        }
        if (t > 0) {
            #pragma unroll
            for (int r = 0; r < 4; ++r) {
                el[w*512 +       r*64 + l] = eA[r];
                el[w*512 + 256 + r*64 + l] = eB[r];
            }
        }
        __syncthreads();                                   // barrier B

        // ---- gates -------------------------------------------------------
        float z0 = zl[0*512 + zi];
        float z1 = zl[1*512 + zi];
        float z2 = zl[2*512 + zi];
        float z3 = zl[3*512 + zi];
        float ig = fsig(z0), fg = fsig(z1), gv = ftanh(z2), og = fsig(z3);
        c_state = fg*c_state + ig*gv;
        float h = og * ftanh(c_state);

        // ---- publish h(t) tagged t+1, fire-and-forget --------------------
        {
            unsigned hhi, hlo; split_bf(h, hhi, hlo);
            cst(hx + ((size_t)(par*NG + g) * 8 + j_pub) * 256 + tau,
                ((ull)(unsigned)(t+1) << 32) | (ull)((hhi<<16)|hlo));
        }

        // ---- off critical path: score partial t-1, softmax update t-2 ----
        if (t > 0) {
            float e = el[0*512+zi] + el[1*512+zi] + el[2*512+zi] + el[3*512+zi] + abj;
            float scp = vj * ftanh(e);
            scp += __shfl_xor(scp,1); scp += __shfl_xor(scp,2);
            scp += __shfl_xor(scp,4); scp += __shfl_xor(scp,8);
            scp += __shfl_xor(scp,16);
            if (sjd == 0)
                cst(spx + (size_t)((t-1)&1)*2048 + g*64 + sb*8 + p,
                    ((ull)(unsigned)t << 32) | (ull)__float_as_uint(scp));
        }
        if (t > 1) {
            const unsigned texp = (unsigned)(t-1);
            int it = 0;
            while ((unsigned)(spr>>32) != texp) {
                if (sdead || ++it > SP_CAP) { sdead = 1; break; }
                spr = cld(spp);
            }
            float s = __uint_as_float((unsigned)spr);
            s += __shfl_xor(s,1); s += __shfl_xor(s,2); s += __shfl_xor(s,4);
            float m_new = fmaxf(m_run, s);
            float sc = __expf(m_run - m_new);
            float wt = __expf(s - m_new);
            l_run = l_run*sc + wt;
            ctx   = ctx*sc + wt*h2v;
            m_run = m_new;
        }
        h2v = h1v; h1v = h;
    }

    // ---- epilogue A: energy/score for SS-1, softmax update for SS-2 ------
    {
        const ull* hr = hx + ((size_t)(((SS-1)&1)*NG + g) * 8) * 256 + tid;
        ull hv[8];
        #pragma unroll
        for (int j = 0; j < 8; ++j) hv[j] = cld(hr + j*256);
        const unsigned texp = (unsigned)SS;
        unsigned need = 0xFFu;
        int rounds = 0;
        while (true) {
            unsigned nn = 0;
            #pragma unroll
            for (int e = 0; e < 8; ++e)
                if (need & (1u<<e))
                    if ((unsigned)(hv[e]>>32) != texp) nn |= (1u<<e);
            need = nn;
            if (!need || sdead) break;
            if (++rounds > H_CAP) { sdead = 1; break; }
            #pragma unroll
            for (int e = 0; e < 8; ++e)
                if (need & (1u<<e)) hv[e] = cld(hr + e*256);
        }
        U4 H, L;
        #pragma unroll
        for (int i = 0; i < 4; ++i) {
            unsigned a = (unsigned)hv[2*i], b_ = (unsigned)hv[2*i+1];
            H.u[i] = (a>>16) | (b_ & 0xFFFF0000u);
            L.u[i] = (a & 0xFFFFu) | (b_<<16);
        }
        *(short8*)(smem + A_HI + wa) = H.s;
        *(short8*)(smem + A_LO + wa) = L.s;
        __syncthreads();

        f32x4 eA = {0.f,0.f,0.f,0.f}, eB = {0.f,0.f,0.f,0.f};
        #pragma unroll
        for (int ks = 0; ks < 8; ++ks) {
            if ((ks>>1) == w) {
                short8 ah = *(const short8*)(smem + A_HI + ks*1024 + l*16);
                short8 al = *(const short8*)(smem + A_LO + ks*1024 + l*16);
                int jj = ks & 1;
                eA = MFMA(ah, BwaH[jj], eA);   eA = MFMA(ah, BwaL[jj], eA);   eA = MFMA(al, BwaH[jj], eA);
                eB = MFMA(ah, BwaH[2+jj], eB); eB = MFMA(ah, BwaL[2+jj], eB); eB = MFMA(al, BwaH[2+jj], eB);
            }
        }
        #pragma unroll
        for (int r = 0; r < 4; ++r) {
            el[w*512 +       r*64 + l] = eA[r];
            el[w*512 + 256 + r*64 + l] = eB[r];
        }
        __syncthreads();

        {   // softmax update for SS-2 (sp slot SS&1, tag SS-1)
            ull* spp2 = spx + (size_t)(SS&1)*2048 + g*64 + sb*8 + (sjd&7);
            ull spr = cld(spp2);
            const unsigned te2 = (unsigned)(SS-1);
            int it = 0;
            while ((unsigned)(spr>>32) != te2) {
                if (sdead || ++it > SP_CAP) { sdead = 1; break; }
                spr = cld(spp2);
            }
            float s = __uint_as_float((unsigned)spr);
            s += __shfl_xor(s,1); s += __shfl_xor(s,2); s += __shfl_xor(s,4);
            float m_new = fmaxf(m_run, s);
            float sc = __expf(m_run - m_new);
            float wt = __expf(s - m_new);
            l_run = l_run*sc + wt;
            ctx   = ctx*sc + wt*h2v;
            m_run = m_new;
        }
        h2v = h1v;
        // score for SS-1 (tag SS)
        float e = el[0*512+zi] + el[1*512+zi] + el[2*512+zi] + el[3*512+zi] + abj;
        float scp = vj * ftanh(e);
        scp += __shfl_xor(scp,1); scp += __shfl_xor(scp,2);
        scp += __shfl_xor(scp,4); scp += __shfl_xor(scp,8);
        scp += __shfl_xor(scp,16);
        if (sjd == 0)
            cst(spx + (size_t)((SS-1)&1)*2048 + g*64 + sb*8 + p,
                ((ull)(unsigned)SS << 32) | (ull)__float_as_uint(scp));
    }

    // ---- epilogue B: softmax update for SS-1, write context --------------
    {
        ull* spp2 = spx + (size_t)((SS-1)&1)*2048 + g*64 + sb*8 + (sjd&7);
        ull spr = cld(spp2);
        const unsigned texp = (unsigned)SS;
        int it = 0;
        while ((unsigned)(spr>>32) != texp) {
            if (sdead || ++it > SP_CAP) { sdead = 1; break; }
            spr = cld(spp2);
        }
        float s = __uint_as_float((unsigned)spr);
        s += __shfl_xor(s,1); s += __shfl_xor(s,2); s += __shfl_xor(s,4);
        float m_new = fmaxf(m_run, s);
        float sc = __expf(m_run - m_new);
        float wt = __expf(s - m_new);
        l_run = l_run*sc + wt;
        ctx   = ctx*sc + wt*h2v;   // h2v == h(SS-1)

        ctxg[(size_t)(b0+sb)*HH + p*32 + sjd] = ctx / l_run;
    }
}

// ---------------------------------------------------------------------------
__global__ __launch_bounds__(64)
void finalize_kernel(const float* __restrict__ ctxg, const float* __restrict__ fcW,
                     const float* __restrict__ fcb, float* __restrict__ out)
{
    __shared__ float cs[HH];
    const int b = blockIdx.x, tid = threadIdx.x;
    *(float4*)&cs[tid*4] = *(const float4*)&ctxg[(size_t)b*HH + tid*4];
    __syncthreads();
    if (tid < OO) {
        float a = fcb[tid];
        #pragma unroll 8
        for (int d = 0; d < HH; ++d) a = fmaf(cs[d], fcW[d*OO + tid], a);
        out[b*OO + tid] = a;
    }
}

// ---------------------------------------------------------------------------
extern "C" void kernel_launch(void* const* d_in, const int* in_sizes, int n_in,
                              void* d_out, int out_size, void* d_ws, size_t ws_size,
                              hipStream_t stream)
{
    const float* x      = (const float*)d_in[0];
    const float* Wi     = (const float*)d_in[1];
    const float* Wh     = (const float*)d_in[2];
    const float* bias   = (const float*)d_in[3];
    const float* attn_W = (const float*)d_in[4];
    const float* attn_b = (const float*)d_in[5];
    const float* v      = (const float*)d_in[6];
    const float* fc_W   = (const float*)d_in[7];
    const float* fc_b   = (const float*)d_in[8];
    float* out = (float*)d_out;

    // workspace: tagged h ring (1MB, consumer-interleaved) + tagged sp ring + ctx
    ull*   hx   = (ull*)d_ws;                  // 2*NG*8*256 = 131072 ull
    ull*   spx  = hx + 2*NG*8*256;             // 2*2048     = 4096 ull
    float* ctxg = (float*)(spx + 4096);        // 65536 floats

    // zero all tags each launch (graph-replay + poison safe)
    hipMemsetAsync(hx, 0, (2*NG*8*256 + 4096) * sizeof(ull), stream);

    lstm_fused_kernel<<<dim3(NG*NP), dim3(256), 0, stream>>>(
        x, Wi, Wh, bias, attn_W, attn_b, v, hx, spx, ctxg);
    finalize_kernel<<<dim3(BB), dim3(64), 0, stream>>>(ctxg, fc_W, fc_b, out);
}